// Round 13
// baseline (130.941 us; speedup 1.0000x reference)
//
#include <hip/hip_runtime.h>

#define LN 8192           // 8194 - 2
#define B_ROWS 4096
#define NMEANS 6

#define COLS_PER_BLOCK 1024   // 256 threads * 4 floats
#define ROWS_PER_BLOCK 64
#define COL_SEGS (LN / COLS_PER_BLOCK)        // 8
#define ROW_CHUNKS (B_ROWS / ROWS_PER_BLOCK)  // 64

typedef float v4f __attribute__((ext_vector_type(4)));

// ---------------------------------------------------------------------------
// Kernel A (CONTROL — R8 tiled-plain best, ~26.7 us in-kernel): correct out.
// ---------------------------------------------------------------------------
__global__ void __launch_bounds__(256)
fused_kernel(const float* __restrict__ w, float* __restrict__ out) {
    const int bid     = blockIdx.x;
    const int colSeg  = bid & (COL_SEGS - 1);        // 0..7
    const int rowBase = (bid >> 3) * ROWS_PER_BLOCK; // 0..4032 step 64

    const int j0 = colSeg * COLS_PER_BLOCK + threadIdx.x * 4;

    const float bk[NMEANS] = {1.99471140f, 1.20985428f, 0.26995483f,
                              0.02215925f, 6.69151e-4f, 7.43360e-6f};
    float a[NMEANS];
#pragma unroll
    for (int k = 0; k < NMEANS; ++k) a[k] = w[k] * bk[k];

    v4f v;
#pragma unroll
    for (int e = 0; e < 4; ++e) {
        float u = (float)(j0 + e) * (5.0f / (float)LN);
        float g = __expf(-0.5f * u * u);
        float E = __expf(u);
        float h = a[5];
        h = h * E + a[4];
        h = h * E + a[3];
        h = h * E + a[2];
        h = h * E + a[1];
        h = h * E + a[0];
        v[e] = g * h;
    }

    float* base = out + (long long)rowBase * LN + j0;
#pragma unroll
    for (int r = 0; r < ROWS_PER_BLOCK; ++r) {
        *(v4f*)(base + (long long)r * LN) = v;
    }
}

// ---------------------------------------------------------------------------
// Probe: nt dwordx4 grid-stride linear stream into d_ws (R11's P2, the
// 7.06 TB/s winner at 512 MB). Launched twice: n4 for 134.2 MB (exactly
// out_size) and n4 for 512 MB. Discriminates d_out-allocation vs size-regime.
// ---------------------------------------------------------------------------
__global__ void __launch_bounds__(256)
probe_nt_x4(float* __restrict__ ws, long long n4) {
    const long long stride = (long long)gridDim.x * blockDim.x;
    const v4f v = {1.0f, 1.0f, 1.0f, 1.0f};
    for (long long i = (long long)blockIdx.x * blockDim.x + threadIdx.x;
         i < n4; i += stride) {
        __builtin_nontemporal_store(v, (v4f*)ws + i);
    }
}

extern "C" void kernel_launch(void* const* d_in, const int* in_sizes, int n_in,
                              void* d_out, int out_size, void* d_ws, size_t ws_size,
                              hipStream_t stream) {
    const float* w = (const float*)d_in[0];   // weights [6]
    float* out = (float*)d_out;

    // A: correct output (control)
    fused_kernel<<<dim3(COL_SEGS * ROW_CHUNKS), dim3(256), 0, stream>>>(w, out);

    // Q1: same-size-as-out nt stream into workspace (134,217,728 B)
    size_t cap = ws_size < (size_t)536870912 ? ws_size : (size_t)536870912;
    long long n4_out = (long long)134217728 / 16;   // 8,388,608 v4f
    long long n4_big = (long long)(cap / 16);       // 512 MB worth
    if (n4_big >= n4_out) {
        probe_nt_x4<<<dim3(256), dim3(256), 0, stream>>>((float*)d_ws, n4_out);
        probe_nt_x4<<<dim3(256), dim3(256), 0, stream>>>((float*)d_ws, n4_big);
    }
}